// Round 1
// baseline (563.965 us; speedup 1.0000x reference)
//
#include <hip/hip_runtime.h>
#include <cstdint>

// ---------------------------------------------------------------------------
// C[m, 0:64] = relu(A[m, 0:K] @ W[K, 64] + bias)   (row-major, ldc-strided C)
// block = 256 threads, tile = 64 rows x 64 cols, 4x4 register blocking
// ---------------------------------------------------------------------------
#define TILE_K 16

__global__ __launch_bounds__(256) void gemm_relu64(
    const float* __restrict__ A, const float* __restrict__ W,
    const float* __restrict__ bias, float* __restrict__ C,
    int M, int K, int lda, int ldc)
{
  __shared__ float As[TILE_K][68];   // k-major
  __shared__ float Ws[TILE_K][68];
  const int tid = threadIdx.x;
  const int m0  = blockIdx.x * 64;
  const int ty  = tid >> 4;          // 0..15 -> rows ty*4..+3
  const int tx  = tid & 15;          // 0..15 -> cols tx*4..+3

  float acc[4][4];
#pragma unroll
  for (int i = 0; i < 4; i++)
#pragma unroll
    for (int j = 0; j < 4; j++) acc[i][j] = 0.f;

  const int ar  = tid >> 2;          // 0..63 tile row (for A load)
  const int ak0 = (tid & 3) * 4;     // 0..12 k offset
  const int wr  = tid >> 4;          // 0..15 k row (for W load)
  const int wc0 = (tid & 15) * 4;    // col offset

  for (int kb = 0; kb < K; kb += TILE_K) {
    // stage A tile (64 x 16), store k-major
    {
      float4 v = make_float4(0.f, 0.f, 0.f, 0.f);
      const int row = m0 + ar;
      const int k   = kb + ak0;
      if (row < M) {
        if (k + 3 < K) {
          v = *reinterpret_cast<const float4*>(A + (size_t)row * lda + k);
        } else {
          float t0 = (k + 0 < K) ? A[(size_t)row * lda + k + 0] : 0.f;
          float t1 = (k + 1 < K) ? A[(size_t)row * lda + k + 1] : 0.f;
          float t2 = (k + 2 < K) ? A[(size_t)row * lda + k + 2] : 0.f;
          float t3 = (k + 3 < K) ? A[(size_t)row * lda + k + 3] : 0.f;
          v = make_float4(t0, t1, t2, t3);
        }
      }
      As[ak0 + 0][ar] = v.x; As[ak0 + 1][ar] = v.y;
      As[ak0 + 2][ar] = v.z; As[ak0 + 3][ar] = v.w;
    }
    // stage W tile (16 x 64)
    {
      float4 v = make_float4(0.f, 0.f, 0.f, 0.f);
      const int k = kb + wr;
      if (k < K) v = *reinterpret_cast<const float4*>(W + (size_t)k * 64 + wc0);
      *reinterpret_cast<float4*>(&Ws[wr][wc0]) = v;
    }
    __syncthreads();
#pragma unroll
    for (int kk = 0; kk < TILE_K; kk++) {
      float4 a = *reinterpret_cast<const float4*>(&As[kk][ty * 4]);
      float4 w = *reinterpret_cast<const float4*>(&Ws[kk][tx * 4]);
      float av[4] = {a.x, a.y, a.z, a.w};
      float wv[4] = {w.x, w.y, w.z, w.w};
#pragma unroll
      for (int i = 0; i < 4; i++)
#pragma unroll
        for (int j = 0; j < 4; j++)
          acc[i][j] = fmaf(av[i], wv[j], acc[i][j]);
    }
    __syncthreads();
  }

  float4 bv = *reinterpret_cast<const float4*>(bias + tx * 4);
  const float bvv[4] = {bv.x, bv.y, bv.z, bv.w};
#pragma unroll
  for (int i = 0; i < 4; i++) {
    const int row = m0 + ty * 4 + i;
    if (row < M) {
      float4 o;
      o.x = fmaxf(acc[i][0] + bvv[0], 0.f);
      o.y = fmaxf(acc[i][1] + bvv[1], 0.f);
      o.z = fmaxf(acc[i][2] + bvv[2], 0.f);
      o.w = fmaxf(acc[i][3] + bvv[3], 0.f);
      *reinterpret_cast<float4*>(C + (size_t)row * ldc + tx * 4) = o;
    }
  }
}

// ---------------------------------------------------------------------------
// Tab[r, 0:64] = relu(nf[r/3] + Eet[r%3, eoff:eoff+64]) @ Wm1half[0:64, 0:64]
// r = n*3 + t ranges over N*3.  (no bias, no output relu)
// ---------------------------------------------------------------------------
__global__ __launch_bounds__(256) void build_table(
    const float* __restrict__ nf, const float* __restrict__ Eet, int eoff,
    const float* __restrict__ Wm1half, float* __restrict__ Tab, int N3)
{
  __shared__ float Es[64][68];   // k-major: Es[k][r]
  __shared__ float Ws[64][68];   // Ws[k][c]
  const int tid = threadIdx.x;
  const int m0  = blockIdx.x * 64;
  const int ty  = tid >> 4, tx = tid & 15;

  // stage input rows: relu(nf[n] + Eet[t])
  {
    const int r = tid >> 2;
    const int rg = m0 + r;
    const int n = rg / 3;
    const int t = rg - n * 3;
#pragma unroll
    for (int j = 0; j < 4; j++) {
      const int k0 = (tid & 3) * 4 + j * 16;
      float4 v = make_float4(0.f, 0.f, 0.f, 0.f);
      if (rg < N3) {
        float4 x = *reinterpret_cast<const float4*>(nf + (size_t)n * 64 + k0);
        float4 e = *reinterpret_cast<const float4*>(Eet + (size_t)t * 128 + eoff + k0);
        v.x = fmaxf(x.x + e.x, 0.f); v.y = fmaxf(x.y + e.y, 0.f);
        v.z = fmaxf(x.z + e.z, 0.f); v.w = fmaxf(x.w + e.w, 0.f);
      }
      Es[k0 + 0][r] = v.x; Es[k0 + 1][r] = v.y;
      Es[k0 + 2][r] = v.z; Es[k0 + 3][r] = v.w;
    }
  }
  // stage weights
  {
    const int kr = tid >> 4, c0 = (tid & 15) * 4;
#pragma unroll
    for (int j = 0; j < 4; j++) {
      const int k = kr + j * 16;
      *reinterpret_cast<float4*>(&Ws[k][c0]) =
          *reinterpret_cast<const float4*>(Wm1half + (size_t)k * 64 + c0);
    }
  }
  __syncthreads();

  float acc[4][4];
#pragma unroll
  for (int i = 0; i < 4; i++)
#pragma unroll
    for (int j = 0; j < 4; j++) acc[i][j] = 0.f;

#pragma unroll 16
  for (int kk = 0; kk < 64; kk++) {
    float4 a = *reinterpret_cast<const float4*>(&Es[kk][ty * 4]);
    float4 w = *reinterpret_cast<const float4*>(&Ws[kk][tx * 4]);
    float av[4] = {a.x, a.y, a.z, a.w};
    float wv[4] = {w.x, w.y, w.z, w.w};
#pragma unroll
    for (int i = 0; i < 4; i++)
#pragma unroll
      for (int j = 0; j < 4; j++)
        acc[i][j] = fmaf(av[i], wv[j], acc[i][j]);
  }

#pragma unroll
  for (int i = 0; i < 4; i++) {
    const int row = m0 + ty * 4 + i;
    if (row < N3) {
      float4 o = make_float4(acc[i][0], acc[i][1], acc[i][2], acc[i][3]);
      *reinterpret_cast<float4*>(Tab + (size_t)row * 64 + tx * 4) = o;
    }
  }
}

// ---------------------------------------------------------------------------
// one wave per edge: logits -> sigmoid -> Bernoulli(u) -> atomic segment sum
// ---------------------------------------------------------------------------
__global__ __launch_bounds__(256) void edge_kernel(
    const int* __restrict__ ei, const int* __restrict__ et,
    const float* __restrict__ u,
    const float* __restrict__ Atab, const float* __restrict__ Btab,
    const float* __restrict__ nf,
    const float* __restrict__ bm1, const float* __restrict__ Wm2,
    const float* __restrict__ bm2,
    float* __restrict__ sums, float* __restrict__ cnt, int E)
{
  const int wid  = (int)((blockIdx.x * (unsigned)blockDim.x + threadIdx.x) >> 6);
  const int lane = threadIdx.x & 63;
  if (wid >= E) return;

  const int sn = ei[wid];
  const int dn = ei[E + wid];
  const int t  = et[wid];

  const float a = Atab[((size_t)sn * 3 + t) * 64 + lane];
  const float b = Btab[((size_t)dn * 3 + t) * 64 + lane];
  const float h = fmaxf(a + b + bm1[lane], 0.f);
  float v = h * Wm2[lane];
#pragma unroll
  for (int off = 32; off; off >>= 1) v += __shfl_xor(v, off, 64);
  const float logits = v + bm2[0];
  const float p = 1.f / (1.f + expf(-logits));

  if (u[wid] < p) {
    atomicAdd(&sums[(size_t)sn * 64 + lane], nf[(size_t)dn * 64 + lane]);
    if (lane == 0) atomicAdd(&cnt[sn], 1.f);
  }
}

// ---------------------------------------------------------------------------
// one wave per node: agg = cnt>0 ? sums/max(cnt,1) : nf;  out = agg @ Wcls + b
// ---------------------------------------------------------------------------
__global__ __launch_bounds__(256) void out_kernel(
    const float* __restrict__ sums, const float* __restrict__ cnt,
    const float* __restrict__ nf,
    const float* __restrict__ Wcls, const float* __restrict__ bcls,
    float* __restrict__ out, int N)
{
  const int n    = (int)((blockIdx.x * (unsigned)blockDim.x + threadIdx.x) >> 6);
  const int lane = threadIdx.x & 63;
  if (n >= N) return;

  const float c = cnt[n];
  const float agg = (c > 0.f)
      ? sums[(size_t)n * 64 + lane] / fmaxf(c, 1.f)
      : nf[(size_t)n * 64 + lane];
  float r0 = agg * Wcls[lane * 2 + 0];
  float r1 = agg * Wcls[lane * 2 + 1];
#pragma unroll
  for (int off = 32; off; off >>= 1) {
    r0 += __shfl_xor(r0, off, 64);
    r1 += __shfl_xor(r1, off, 64);
  }
  if (lane == 0) {
    out[(size_t)n * 2 + 0] = r0 + bcls[0];
    out[(size_t)n * 2 + 1] = r1 + bcls[1];
  }
}

// ---------------------------------------------------------------------------
extern "C" void kernel_launch(void* const* d_in, const int* in_sizes, int n_in,
                              void* d_out, int out_size, void* d_ws, size_t ws_size,
                              hipStream_t stream)
{
  const float* image    = (const float*)d_in[0];
  const float* tweets   = (const float*)d_in[1];
  const float* num_prop = (const float*)d_in[2];
  const float* category = (const float*)d_in[3];
  const int*   ei       = (const int*)  d_in[4];
  const int*   et       = (const int*)  d_in[5];
  // d_in[6] = eps : unused (z is dead code)
  const float* u        = (const float*)d_in[7];
  const float* Wi  = (const float*)d_in[8],  *bi  = (const float*)d_in[9];
  const float* Wt  = (const float*)d_in[10], *bt  = (const float*)d_in[11];
  const float* Wn  = (const float*)d_in[12], *bn  = (const float*)d_in[13];
  const float* Wc  = (const float*)d_in[14], *bc  = (const float*)d_in[15];
  const float* Wf  = (const float*)d_in[16], *bf  = (const float*)d_in[17];
  const float* Eet = (const float*)d_in[18];
  // d_in[19..22] = Wmu,bmu,Wlv,blv : unused (z is dead code)
  const float* Wm1 = (const float*)d_in[23], *bm1 = (const float*)d_in[24];
  const float* Wm2 = (const float*)d_in[25], *bm2 = (const float*)d_in[26];
  const float* Wcls= (const float*)d_in[27], *bcls= (const float*)d_in[28];
  float* out = (float*)d_out;

  const int N = in_sizes[0] / 512;
  const int E = in_sizes[5];

  float* ws = (float*)d_ws;
  size_t off = 0;
  float* concat = ws + off;  off += (size_t)N * 256;
  float* nf     = ws + off;  off += (size_t)N * 64;
  float* Atab   = ws + off;  off += (size_t)N * 3 * 64;
  float* Btab   = ws + off;  off += (size_t)N * 3 * 64;
  float* sums   = ws + off;  off += (size_t)N * 64;
  float* cnt    = ws + off;  off += (size_t)N;

  // zero the accumulators (sums + cnt are contiguous)
  hipMemsetAsync(sums, 0, (size_t)(N * 64 + N) * sizeof(float), stream);

  const int gN = (N + 63) / 64;
  gemm_relu64<<<gN, 256, 0, stream>>>(image,    Wi, bi, concat + 0,   N, 512, 512, 256);
  gemm_relu64<<<gN, 256, 0, stream>>>(tweets,   Wt, bt, concat + 64,  N, 768, 768, 256);
  gemm_relu64<<<gN, 256, 0, stream>>>(num_prop, Wn, bn, concat + 128, N, 16,  16,  256);
  gemm_relu64<<<gN, 256, 0, stream>>>(category, Wc, bc, concat + 192, N, 8,   8,   256);
  gemm_relu64<<<gN, 256, 0, stream>>>(concat,   Wf, bf, nf,           N, 256, 256, 64);

  const int N3 = N * 3;
  const int gT = (N3 + 63) / 64;
  build_table<<<gT, 256, 0, stream>>>(nf, Eet, 0,  Wm1,            Atab, N3);
  build_table<<<gT, 256, 0, stream>>>(nf, Eet, 64, Wm1 + 64 * 64,  Btab, N3);

  edge_kernel<<<(E + 3) / 4, 256, 0, stream>>>(ei, et, u, Atab, Btab, nf,
                                               bm1, Wm2, bm2, sums, cnt, E);

  out_kernel<<<(N + 3) / 4, 256, 0, stream>>>(sums, cnt, nf, Wcls, bcls, out, N);
}